// Round 2
// baseline (2433.589 us; speedup 1.0000x reference)
//
#include <hip/hip_runtime.h>
#include <hip/hip_bf16.h>

// CircuitGNN: 3-layer GCN (N=500k, E=1M, H=64) + mean pool + tanh FC head.
//   - GCN layer = S @ h @ W + b; aggregate-first (a = S@h via CSR gather), then a@W.
//   - CSR built per call (deg histogram -> scan -> fill).
//   - mm64 v2: M=64/block, 4x4 thread tile, 32 KB LDS (5 blocks/CU), swizzled
//     k-major A tile (conflict-free staging + reads), full k-unroll.
// All fp32 (no fp32 MFMA on CDNA4).

#define ALIGN256(x) (((x) + 255) & ~(size_t)255)

__global__ __launch_bounds__(256) void deg_kernel(const int* __restrict__ dst, int* __restrict__ cnt, int E) {
    int e = blockIdx.x * 256 + threadIdx.x;
    if (e < E) atomicAdd(&cnt[dst[e]], 1);
}

__global__ __launch_bounds__(256) void dinv_kernel(const int* __restrict__ cnt, float* __restrict__ dinv, int N) {
    int i = blockIdx.x * 256 + threadIdx.x;
    if (i < N) dinv[i] = rsqrtf((float)(cnt[i] + 1));   // +1 = self loop
}

// ---- 2-level exclusive scan over cnt[N] ----
__global__ __launch_bounds__(256) void scan1_kernel(const int* __restrict__ cnt, int* __restrict__ bsum, int N) {
    __shared__ int s[256];
    int t = threadIdx.x, b = blockIdx.x;
    int i0 = b * 1024 + t * 4;
    int v = 0;
    if (i0 + 3 < N) { int4 q = *(const int4*)&cnt[i0]; v = q.x + q.y + q.z + q.w; }
    else { for (int k = 0; k < 4; ++k) if (i0 + k < N) v += cnt[i0 + k]; }
    s[t] = v; __syncthreads();
    for (int o = 128; o > 0; o >>= 1) { if (t < o) s[t] += s[t + o]; __syncthreads(); }
    if (t == 0) bsum[b] = s[0];
}

__global__ __launch_bounds__(512) void scan2_kernel(const int* __restrict__ bsum, int* __restrict__ bbase, int nb) {
    __shared__ int s[512];
    int t = threadIdx.x;
    int v = (t < nb) ? bsum[t] : 0;
    s[t] = v; __syncthreads();
    for (int off = 1; off < 512; off <<= 1) {
        int u = 0; if (t >= off) u = s[t - off];
        __syncthreads(); s[t] += u; __syncthreads();
    }
    if (t < nb) bbase[t] = s[t] - v;   // exclusive
}

__global__ __launch_bounds__(256) void scan3_kernel(const int* __restrict__ cnt, const int* __restrict__ bbase,
                                                    int* __restrict__ offs, int* __restrict__ cur, int N) {
    __shared__ int s[256];
    int t = threadIdx.x, b = blockIdx.x;
    int i0 = b * 1024 + t * 4;
    int v0 = 0, v1 = 0, v2 = 0, v3 = 0;
    if (i0 + 3 < N) { int4 q = *(const int4*)&cnt[i0]; v0 = q.x; v1 = q.y; v2 = q.z; v3 = q.w; }
    else {
        if (i0 < N) v0 = cnt[i0];
        if (i0 + 1 < N) v1 = cnt[i0 + 1];
        if (i0 + 2 < N) v2 = cnt[i0 + 2];
        if (i0 + 3 < N) v3 = cnt[i0 + 3];
    }
    int ts = v0 + v1 + v2 + v3;
    s[t] = ts; __syncthreads();
    for (int off = 1; off < 256; off <<= 1) {
        int u = 0; if (t >= off) u = s[t - off];
        __syncthreads(); s[t] += u; __syncthreads();
    }
    int ex = s[t] - ts + bbase[b];
    int o0 = ex, o1 = ex + v0, o2 = o1 + v1, o3 = o2 + v2;
    if (i0     < N) { offs[i0]     = o0; cur[i0]     = o0; }
    if (i0 + 1 < N) { offs[i0 + 1] = o1; cur[i0 + 1] = o1; }
    if (i0 + 2 < N) { offs[i0 + 2] = o2; cur[i0 + 2] = o2; }
    if (i0 + 3 < N) { offs[i0 + 3] = o3; cur[i0 + 3] = o3; }
}

__global__ __launch_bounds__(256) void fill_kernel(const int* __restrict__ ei, int* __restrict__ cur,
                                                   int* __restrict__ csr, int E) {
    int e = blockIdx.x * 256 + threadIdx.x;
    if (e < E) {
        int s = ei[e], d = ei[E + e];
        int p = atomicAdd(&cur[d], 1);
        csr[p] = s;
    }
}

// ---- layer 1: aggregate raw 3-wide x (thread per node) ----
__global__ __launch_bounds__(256) void agg1_kernel(const float* __restrict__ x, const float* __restrict__ dinv,
                                                   const int* __restrict__ offs, const int* __restrict__ cnt,
                                                   const int* __restrict__ csr, float* __restrict__ a1, int N) {
    int j = blockIdx.x * 256 + threadIdx.x;
    if (j >= N) return;
    float dj = dinv[j];
    float s0 = dj * x[(size_t)j * 3 + 0];
    float s1 = dj * x[(size_t)j * 3 + 1];
    float s2 = dj * x[(size_t)j * 3 + 2];
    int off = offs[j], deg = cnt[j];
    for (int i = 0; i < deg; ++i) {
        int s = csr[off + i];
        float ds = dinv[s];
        s0 += ds * x[(size_t)s * 3 + 0];
        s1 += ds * x[(size_t)s * 3 + 1];
        s2 += ds * x[(size_t)s * 3 + 2];
    }
    a1[(size_t)j * 4 + 0] = dj * s0;
    a1[(size_t)j * 4 + 1] = dj * s1;
    a1[(size_t)j * 4 + 2] = dj * s2;
}

// ---- layer 1 matmul 3->64, wave per node, fused bias+relu ----
__global__ __launch_bounds__(256) void mm1_kernel(const float* __restrict__ a1, const float* __restrict__ W1,
                                                  const float* __restrict__ b1, float* __restrict__ h, int N) {
    int j = blockIdx.x * 4 + (threadIdx.x >> 6);
    int l = threadIdx.x & 63;
    if (j >= N) return;
    float v = b1[l]
            + a1[(size_t)j * 4 + 0] * W1[l]
            + a1[(size_t)j * 4 + 1] * W1[64 + l]
            + a1[(size_t)j * 4 + 2] * W1[128 + l];
    h[(size_t)j * 64 + l] = fmaxf(v, 0.f);
}

// ---- 64-wide aggregation: wave per node, lane = feature ----
__global__ __launch_bounds__(256) void agg64_kernel(const float* __restrict__ h, const float* __restrict__ dinv,
                                                    const int* __restrict__ offs, const int* __restrict__ cnt,
                                                    const int* __restrict__ csr, float* __restrict__ a, int N) {
    int j = blockIdx.x * 4 + (threadIdx.x >> 6);
    int l = threadIdx.x & 63;
    if (j >= N) return;
    float dj = dinv[j];
    float acc = dj * h[(size_t)j * 64 + l];
    int off = offs[j], deg = cnt[j];
    int i = 0;
    for (; i + 1 < deg; i += 2) {
        int s0 = csr[off + i], s1 = csr[off + i + 1];
        float d0 = dinv[s0], d1 = dinv[s1];
        acc += d0 * h[(size_t)s0 * 64 + l];
        acc += d1 * h[(size_t)s1 * 64 + l];
    }
    if (i < deg) {
        int s0 = csr[off + i];
        acc += dinv[s0] * h[(size_t)s0 * 64 + l];
    }
    a[(size_t)j * 64 + l] = dj * acc;
}

// ---- mm64 v2: block = 64 nodes x 64 cols, 256 threads, 4x4 per thread.
//      LDS 32 KB total -> 5 blocks/CU. A tile k-major with rotation swizzle:
//      idx(k,n) = k*64 + ((n + 4*(k>>2)) & 63)  -> staging writes hit all 32
//      banks 2-way (free), reads stay b128-contiguous. W verbatim 64x64.
//      POOL=1 fuses mean-pool accumulation instead of storing h3. ----
template <int POOL>
__global__ __launch_bounds__(256) void mm64_kernel(const float* __restrict__ A, const float* __restrict__ W,
                                                   const float* __restrict__ bias, float* __restrict__ out,
                                                   float* __restrict__ pool, int N) {
    __shared__ float aS[64 * 64];
    __shared__ float Ws[64 * 64];
    const int t = threadIdx.x;
    const int nb = blockIdx.x * 64;

    // stage W verbatim (coalesced float4, 2-way banks = free)
    #pragma unroll
    for (int it = 0; it < 4; ++it) {
        int f4 = it * 256 + t;
        *(float4*)&Ws[f4 * 4] = *(const float4*)&W[f4 * 4];
    }
    // stage A transposed+swizzled: thread reads A[nb+n][4kc..4kc+3] (coalesced),
    // writes k-major with rotation (bank = (n + 4kc) & 31 -> 2-way, free)
    #pragma unroll
    for (int it = 0; it < 4; ++it) {
        int f4 = it * 256 + t;
        int n = f4 >> 4, kc = f4 & 15;
        int gn = nb + n;
        float4 v = make_float4(0.f, 0.f, 0.f, 0.f);
        if (gn < N) v = *(const float4*)&A[(size_t)gn * 64 + kc * 4];
        int ns = (n + 4 * kc) & 63;
        aS[(4 * kc + 0) * 64 + ns] = v.x;
        aS[(4 * kc + 1) * 64 + ns] = v.y;
        aS[(4 * kc + 2) * 64 + ns] = v.z;
        aS[(4 * kc + 3) * 64 + ns] = v.w;
    }
    __syncthreads();

    const int tx = t & 15, ty = t >> 4;   // cols 4*tx..+3, nodes 4*ty..+3
    float4 acc0 = make_float4(0.f, 0.f, 0.f, 0.f);
    float4 acc1 = acc0, acc2 = acc0, acc3 = acc0;

    #pragma unroll
    for (int k = 0; k < 64; ++k) {
        float4 w4 = *(const float4*)&Ws[k * 64 + (tx << 2)];
        float4 a4 = *(const float4*)&aS[k * 64 + (((ty << 2) + ((k >> 2) << 2)) & 63)];
        acc0.x += a4.x * w4.x; acc0.y += a4.x * w4.y; acc0.z += a4.x * w4.z; acc0.w += a4.x * w4.w;
        acc1.x += a4.y * w4.x; acc1.y += a4.y * w4.y; acc1.z += a4.y * w4.z; acc1.w += a4.y * w4.w;
        acc2.x += a4.z * w4.x; acc2.y += a4.z * w4.y; acc2.z += a4.z * w4.z; acc2.w += a4.z * w4.w;
        acc3.x += a4.w * w4.x; acc3.y += a4.w * w4.y; acc3.z += a4.w * w4.z; acc3.w += a4.w * w4.w;
    }

    float4 bb = *(const float4*)&bias[tx << 2];
    float4 r0, r1, r2, r3;
    r0.x = fmaxf(acc0.x + bb.x, 0.f); r0.y = fmaxf(acc0.y + bb.y, 0.f); r0.z = fmaxf(acc0.z + bb.z, 0.f); r0.w = fmaxf(acc0.w + bb.w, 0.f);
    r1.x = fmaxf(acc1.x + bb.x, 0.f); r1.y = fmaxf(acc1.y + bb.y, 0.f); r1.z = fmaxf(acc1.z + bb.z, 0.f); r1.w = fmaxf(acc1.w + bb.w, 0.f);
    r2.x = fmaxf(acc2.x + bb.x, 0.f); r2.y = fmaxf(acc2.y + bb.y, 0.f); r2.z = fmaxf(acc2.z + bb.z, 0.f); r2.w = fmaxf(acc2.w + bb.w, 0.f);
    r3.x = fmaxf(acc3.x + bb.x, 0.f); r3.y = fmaxf(acc3.y + bb.y, 0.f); r3.z = fmaxf(acc3.z + bb.z, 0.f); r3.w = fmaxf(acc3.w + bb.w, 0.f);

    int n0 = nb + (ty << 2);
    if (POOL) {
        float4 ps = make_float4(0.f, 0.f, 0.f, 0.f);
        if (n0     < N) { ps.x += r0.x; ps.y += r0.y; ps.z += r0.z; ps.w += r0.w; }
        if (n0 + 1 < N) { ps.x += r1.x; ps.y += r1.y; ps.z += r1.z; ps.w += r1.w; }
        if (n0 + 2 < N) { ps.x += r2.x; ps.y += r2.y; ps.z += r2.z; ps.w += r2.w; }
        if (n0 + 3 < N) { ps.x += r3.x; ps.y += r3.y; ps.z += r3.z; ps.w += r3.w; }
        __syncthreads();                  // done reading aS; reuse as reduce scratch
        float* red = aS;
        *(float4*)&red[t * 4] = ps;
        __syncthreads();
        if (ty == 0) {                    // t == tx, 16 threads
            float4 s = make_float4(0.f, 0.f, 0.f, 0.f);
            for (int i = 0; i < 16; ++i) {
                float4 q = *(const float4*)&red[(i * 16 + tx) * 4];
                s.x += q.x; s.y += q.y; s.z += q.z; s.w += q.w;
            }
            atomicAdd(&pool[(tx << 2) + 0], s.x);
            atomicAdd(&pool[(tx << 2) + 1], s.y);
            atomicAdd(&pool[(tx << 2) + 2], s.z);
            atomicAdd(&pool[(tx << 2) + 3], s.w);
        }
    } else {
        if (n0     < N) *(float4*)&out[(size_t)(n0    ) * 64 + (tx << 2)] = r0;
        if (n0 + 1 < N) *(float4*)&out[(size_t)(n0 + 1) * 64 + (tx << 2)] = r1;
        if (n0 + 2 < N) *(float4*)&out[(size_t)(n0 + 2) * 64 + (tx << 2)] = r2;
        if (n0 + 3 < N) *(float4*)&out[(size_t)(n0 + 3) * 64 + (tx << 2)] = r3;
    }
}

__global__ __launch_bounds__(64) void final_kernel(const float* __restrict__ pool, const float* __restrict__ Wfc,
                                                   const float* __restrict__ bfc, float* __restrict__ out, int N) {
    int t = threadIdx.x;
    if (t < 24) {
        float inv = 1.0f / (float)N;
        float s = bfc[t];
        for (int c = 0; c < 64; ++c) s += pool[c] * inv * Wfc[c * 24 + t];
        out[t] = tanhf(s);
    }
}

extern "C" void kernel_launch(void* const* d_in, const int* in_sizes, int n_in,
                              void* d_out, int out_size, void* d_ws, size_t ws_size,
                              hipStream_t stream) {
    const float* x   = (const float*)d_in[0];
    const int*   ei  = (const int*)d_in[1];     // (2,E): row0 = src, row1 = dst
    // d_in[2] = batch (all zeros) -- unused
    const float* W1  = (const float*)d_in[3];
    const float* b1  = (const float*)d_in[4];
    const float* W2  = (const float*)d_in[5];
    const float* b2  = (const float*)d_in[6];
    const float* W3  = (const float*)d_in[7];
    const float* b3  = (const float*)d_in[8];
    const float* Wfc = (const float*)d_in[9];
    const float* bfc = (const float*)d_in[10];
    float* out = (float*)d_out;

    const int N = in_sizes[2];          // batch length = num nodes
    const int E = in_sizes[1] / 2;

    size_t off = 0;
    auto take = [&](size_t bytes) -> char* {
        char* p = (char*)d_ws + off;
        off = ALIGN256(off + bytes);
        return p;
    };
    int*   cnt   = (int*)  take((size_t)N * 4);
    float* dinv  = (float*)take((size_t)N * 4);
    int*   offs  = (int*)  take((size_t)N * 4);
    int*   cur   = (int*)  take((size_t)N * 4);
    int*   bsum  = (int*)  take(512 * 4);
    int*   bbase = (int*)  take(512 * 4);
    float* pool  = (float*)take(64 * 4);
    int*   csr   = (int*)  take((size_t)E * 4);
    float* hbuf  = (float*)take((size_t)N * 64 * 4);
    float* abuf  = (float*)take((size_t)N * 64 * 4);
    (void)ws_size; (void)n_in; (void)out_size;

    const int NB = (N + 1023) / 1024;   // <= 512 for N <= 512k

    hipMemsetAsync(cnt, 0, (size_t)N * 4, stream);
    hipMemsetAsync(pool, 0, 64 * 4, stream);

    deg_kernel <<<(E + 255) / 256, 256, 0, stream>>>(ei + E, cnt, E);
    dinv_kernel<<<(N + 255) / 256, 256, 0, stream>>>(cnt, dinv, N);
    scan1_kernel<<<NB, 256, 0, stream>>>(cnt, bsum, N);
    scan2_kernel<<<1, 512, 0, stream>>>(bsum, bbase, NB);
    scan3_kernel<<<NB, 256, 0, stream>>>(cnt, bbase, offs, cur, N);
    fill_kernel<<<(E + 255) / 256, 256, 0, stream>>>(ei, cur, csr, E);

    // layer 1: a1 = S@x (3-wide), h = relu(a1@W1 + b1)
    agg1_kernel<<<(N + 255) / 256, 256, 0, stream>>>(x, dinv, offs, cnt, csr, abuf, N);
    mm1_kernel <<<(N + 3) / 4, 256, 0, stream>>>(abuf, W1, b1, hbuf, N);

    // layer 2
    agg64_kernel<<<(N + 3) / 4, 256, 0, stream>>>(hbuf, dinv, offs, cnt, csr, abuf, N);
    mm64_kernel<0><<<(N + 63) / 64, 256, 0, stream>>>(abuf, W2, b2, hbuf, nullptr, N);

    // layer 3 (matmul fused with mean-pool accumulation)
    agg64_kernel<<<(N + 3) / 4, 256, 0, stream>>>(hbuf, dinv, offs, cnt, csr, abuf, N);
    mm64_kernel<1><<<(N + 63) / 64, 256, 0, stream>>>(abuf, W3, b3, nullptr, pool, N);

    final_kernel<<<1, 64, 0, stream>>>(pool, Wfc, bfc, out, N);
}

// Round 3
// 735.620 us; speedup vs baseline: 3.3082x; 3.3082x over previous
//
#include <hip/hip_runtime.h>
#include <hip/hip_bf16.h>

// CircuitGNN: 3-layer GCN (N=500k, E=1M, H=64) + mean pool + tanh FC head.
//   - GCN layer = S @ h @ W + b; aggregate-first (a = S@h via CSR gather), then a@W.
//   - CSR built per call (deg histogram -> scan -> fill).
//   - mm64 v3: NO LDS tile. W register-stationary per wave (lane = column,
//     64 VGPRs), wave grid-strides nodes; A row broadcast via v_readlane.
//     No barriers, no transpose. v2's swizzled-LDS full-unroll spilled
//     (VGPR=256, 1.9 GB scratch traffic) -- do not reintroduce.
// All fp32 (no fp32 MFMA on CDNA4).

#define ALIGN256(x) (((x) + 255) & ~(size_t)255)

__device__ __forceinline__ float rl(float v, int lane) {
    return __builtin_bit_cast(float, __builtin_amdgcn_readlane(__builtin_bit_cast(int, v), lane));
}

__global__ __launch_bounds__(256) void deg_kernel(const int* __restrict__ dst, int* __restrict__ cnt, int E) {
    int e = blockIdx.x * 256 + threadIdx.x;
    if (e < E) atomicAdd(&cnt[dst[e]], 1);
}

__global__ __launch_bounds__(256) void dinv_kernel(const int* __restrict__ cnt, float* __restrict__ dinv, int N) {
    int i = blockIdx.x * 256 + threadIdx.x;
    if (i < N) dinv[i] = rsqrtf((float)(cnt[i] + 1));   // +1 = self loop
}

// ---- 2-level exclusive scan over cnt[N] ----
__global__ __launch_bounds__(256) void scan1_kernel(const int* __restrict__ cnt, int* __restrict__ bsum, int N) {
    __shared__ int s[256];
    int t = threadIdx.x, b = blockIdx.x;
    int i0 = b * 1024 + t * 4;
    int v = 0;
    if (i0 + 3 < N) { int4 q = *(const int4*)&cnt[i0]; v = q.x + q.y + q.z + q.w; }
    else { for (int k = 0; k < 4; ++k) if (i0 + k < N) v += cnt[i0 + k]; }
    s[t] = v; __syncthreads();
    for (int o = 128; o > 0; o >>= 1) { if (t < o) s[t] += s[t + o]; __syncthreads(); }
    if (t == 0) bsum[b] = s[0];
}

__global__ __launch_bounds__(512) void scan2_kernel(const int* __restrict__ bsum, int* __restrict__ bbase, int nb) {
    __shared__ int s[512];
    int t = threadIdx.x;
    int v = (t < nb) ? bsum[t] : 0;
    s[t] = v; __syncthreads();
    for (int off = 1; off < 512; off <<= 1) {
        int u = 0; if (t >= off) u = s[t - off];
        __syncthreads(); s[t] += u; __syncthreads();
    }
    if (t < nb) bbase[t] = s[t] - v;   // exclusive
}

__global__ __launch_bounds__(256) void scan3_kernel(const int* __restrict__ cnt, const int* __restrict__ bbase,
                                                    int* __restrict__ offs, int* __restrict__ cur, int N) {
    __shared__ int s[256];
    int t = threadIdx.x, b = blockIdx.x;
    int i0 = b * 1024 + t * 4;
    int v0 = 0, v1 = 0, v2 = 0, v3 = 0;
    if (i0 + 3 < N) { int4 q = *(const int4*)&cnt[i0]; v0 = q.x; v1 = q.y; v2 = q.z; v3 = q.w; }
    else {
        if (i0 < N) v0 = cnt[i0];
        if (i0 + 1 < N) v1 = cnt[i0 + 1];
        if (i0 + 2 < N) v2 = cnt[i0 + 2];
        if (i0 + 3 < N) v3 = cnt[i0 + 3];
    }
    int ts = v0 + v1 + v2 + v3;
    s[t] = ts; __syncthreads();
    for (int off = 1; off < 256; off <<= 1) {
        int u = 0; if (t >= off) u = s[t - off];
        __syncthreads(); s[t] += u; __syncthreads();
    }
    int ex = s[t] - ts + bbase[b];
    int o0 = ex, o1 = ex + v0, o2 = o1 + v1, o3 = o2 + v2;
    if (i0     < N) { offs[i0]     = o0; cur[i0]     = o0; }
    if (i0 + 1 < N) { offs[i0 + 1] = o1; cur[i0 + 1] = o1; }
    if (i0 + 2 < N) { offs[i0 + 2] = o2; cur[i0 + 2] = o2; }
    if (i0 + 3 < N) { offs[i0 + 3] = o3; cur[i0 + 3] = o3; }
}

__global__ __launch_bounds__(256) void fill_kernel(const int* __restrict__ ei, int* __restrict__ cur,
                                                   int* __restrict__ csr, int E) {
    int e = blockIdx.x * 256 + threadIdx.x;
    if (e < E) {
        int s = ei[e], d = ei[E + e];
        int p = atomicAdd(&cur[d], 1);
        csr[p] = s;
    }
}

// ---- layer 1: aggregate raw 3-wide x (thread per node) ----
__global__ __launch_bounds__(256) void agg1_kernel(const float* __restrict__ x, const float* __restrict__ dinv,
                                                   const int* __restrict__ offs, const int* __restrict__ cnt,
                                                   const int* __restrict__ csr, float* __restrict__ a1, int N) {
    int j = blockIdx.x * 256 + threadIdx.x;
    if (j >= N) return;
    float dj = dinv[j];
    float s0 = dj * x[(size_t)j * 3 + 0];
    float s1 = dj * x[(size_t)j * 3 + 1];
    float s2 = dj * x[(size_t)j * 3 + 2];
    int off = offs[j], deg = cnt[j];
    for (int i = 0; i < deg; ++i) {
        int s = csr[off + i];
        float ds = dinv[s];
        s0 += ds * x[(size_t)s * 3 + 0];
        s1 += ds * x[(size_t)s * 3 + 1];
        s2 += ds * x[(size_t)s * 3 + 2];
    }
    a1[(size_t)j * 4 + 0] = dj * s0;
    a1[(size_t)j * 4 + 1] = dj * s1;
    a1[(size_t)j * 4 + 2] = dj * s2;
}

// ---- layer 1 matmul 3->64, wave per node, fused bias+relu ----
__global__ __launch_bounds__(256) void mm1_kernel(const float* __restrict__ a1, const float* __restrict__ W1,
                                                  const float* __restrict__ b1, float* __restrict__ h, int N) {
    int j = blockIdx.x * 4 + (threadIdx.x >> 6);
    int l = threadIdx.x & 63;
    if (j >= N) return;
    float v = b1[l]
            + a1[(size_t)j * 4 + 0] * W1[l]
            + a1[(size_t)j * 4 + 1] * W1[64 + l]
            + a1[(size_t)j * 4 + 2] * W1[128 + l];
    h[(size_t)j * 64 + l] = fmaxf(v, 0.f);
}

// ---- 64-wide aggregation: wave per node, lane = feature ----
__global__ __launch_bounds__(256) void agg64_kernel(const float* __restrict__ h, const float* __restrict__ dinv,
                                                    const int* __restrict__ offs, const int* __restrict__ cnt,
                                                    const int* __restrict__ csr, float* __restrict__ a, int N) {
    int j = blockIdx.x * 4 + (threadIdx.x >> 6);
    int l = threadIdx.x & 63;
    if (j >= N) return;
    float dj = dinv[j];
    float acc = dj * h[(size_t)j * 64 + l];
    int off = offs[j], deg = cnt[j];
    int i = 0;
    for (; i + 1 < deg; i += 2) {
        int s0 = csr[off + i], s1 = csr[off + i + 1];
        float d0 = dinv[s0], d1 = dinv[s1];
        acc += d0 * h[(size_t)s0 * 64 + l];
        acc += d1 * h[(size_t)s1 * 64 + l];
    }
    if (i < deg) {
        int s0 = csr[off + i];
        acc += dinv[s0] * h[(size_t)s0 * 64 + l];
    }
    a[(size_t)j * 64 + l] = dj * acc;
}

// ---- mm64 v3: wave grid-strides nodes; W register-stationary (lane = col,
//      w[k] = W[k][lane], 64 VGPRs); A row broadcast via v_readlane.
//      POOL=1 accumulates mean-pool in-register, block-reduces at end. ----
template <int POOL>
__global__ __launch_bounds__(256) void mm64_kernel(const float* __restrict__ A, const float* __restrict__ W,
                                                   const float* __restrict__ bias, float* __restrict__ out,
                                                   float* __restrict__ pool, int N) {
    const int l = threadIdx.x & 63;
    const int wave = blockIdx.x * 4 + (threadIdx.x >> 6);
    const int stride = gridDim.x * 4;

    // W column into registers (hot in L2 after first wave; 64 coalesced loads)
    float w[64];
    #pragma unroll
    for (int k = 0; k < 64; ++k) w[k] = W[k * 64 + l];
    const float bl = bias[l];

    float ps = 0.f;
    int j = wave;
    float a = (j < N) ? A[(size_t)j * 64 + l] : 0.f;
    while (j < N) {
        int jn = j + stride;
        float a_next = (jn < N) ? A[(size_t)jn * 64 + l] : 0.f;

        float acc0 = 0.f, acc1 = 0.f, acc2 = 0.f, acc3 = 0.f;
        #pragma unroll
        for (int k = 0; k < 64; k += 4) {
            acc0 = fmaf(rl(a, k + 0), w[k + 0], acc0);
            acc1 = fmaf(rl(a, k + 1), w[k + 1], acc1);
            acc2 = fmaf(rl(a, k + 2), w[k + 2], acc2);
            acc3 = fmaf(rl(a, k + 3), w[k + 3], acc3);
        }
        float r = fmaxf((acc0 + acc1) + (acc2 + acc3) + bl, 0.f);
        if (POOL) ps += r;
        else out[(size_t)j * 64 + l] = r;

        j = jn;
        a = a_next;
    }

    if (POOL) {
        __shared__ float red[256];
        red[threadIdx.x] = ps;
        __syncthreads();
        if (threadIdx.x < 64) {
            float s = red[threadIdx.x] + red[64 + threadIdx.x]
                    + red[128 + threadIdx.x] + red[192 + threadIdx.x];
            atomicAdd(&pool[threadIdx.x], s);
        }
    }
}

__global__ __launch_bounds__(64) void final_kernel(const float* __restrict__ pool, const float* __restrict__ Wfc,
                                                   const float* __restrict__ bfc, float* __restrict__ out, int N) {
    int t = threadIdx.x;
    if (t < 24) {
        float inv = 1.0f / (float)N;
        float s = bfc[t];
        for (int c = 0; c < 64; ++c) s += pool[c] * inv * Wfc[c * 24 + t];
        out[t] = tanhf(s);
    }
}

extern "C" void kernel_launch(void* const* d_in, const int* in_sizes, int n_in,
                              void* d_out, int out_size, void* d_ws, size_t ws_size,
                              hipStream_t stream) {
    const float* x   = (const float*)d_in[0];
    const int*   ei  = (const int*)d_in[1];     // (2,E): row0 = src, row1 = dst
    // d_in[2] = batch (all zeros) -- unused
    const float* W1  = (const float*)d_in[3];
    const float* b1  = (const float*)d_in[4];
    const float* W2  = (const float*)d_in[5];
    const float* b2  = (const float*)d_in[6];
    const float* W3  = (const float*)d_in[7];
    const float* b3  = (const float*)d_in[8];
    const float* Wfc = (const float*)d_in[9];
    const float* bfc = (const float*)d_in[10];
    float* out = (float*)d_out;

    const int N = in_sizes[2];          // batch length = num nodes
    const int E = in_sizes[1] / 2;

    size_t off = 0;
    auto take = [&](size_t bytes) -> char* {
        char* p = (char*)d_ws + off;
        off = ALIGN256(off + bytes);
        return p;
    };
    int*   cnt   = (int*)  take((size_t)N * 4);
    float* dinv  = (float*)take((size_t)N * 4);
    int*   offs  = (int*)  take((size_t)N * 4);
    int*   cur   = (int*)  take((size_t)N * 4);
    int*   bsum  = (int*)  take(512 * 4);
    int*   bbase = (int*)  take(512 * 4);
    float* pool  = (float*)take(64 * 4);
    int*   csr   = (int*)  take((size_t)E * 4);
    float* hbuf  = (float*)take((size_t)N * 64 * 4);
    float* abuf  = (float*)take((size_t)N * 64 * 4);
    (void)ws_size; (void)n_in; (void)out_size;

    const int NB = (N + 1023) / 1024;   // <= 512 for N <= 512k

    hipMemsetAsync(cnt, 0, (size_t)N * 4, stream);
    hipMemsetAsync(pool, 0, 64 * 4, stream);

    deg_kernel <<<(E + 255) / 256, 256, 0, stream>>>(ei + E, cnt, E);
    dinv_kernel<<<(N + 255) / 256, 256, 0, stream>>>(cnt, dinv, N);
    scan1_kernel<<<NB, 256, 0, stream>>>(cnt, bsum, N);
    scan2_kernel<<<1, 512, 0, stream>>>(bsum, bbase, NB);
    scan3_kernel<<<NB, 256, 0, stream>>>(cnt, bbase, offs, cur, N);
    fill_kernel<<<(E + 255) / 256, 256, 0, stream>>>(ei, cur, csr, E);

    // layer 1: a1 = S@x (3-wide), h = relu(a1@W1 + b1)
    agg1_kernel<<<(N + 255) / 256, 256, 0, stream>>>(x, dinv, offs, cnt, csr, abuf, N);
    mm1_kernel <<<(N + 3) / 4, 256, 0, stream>>>(abuf, W1, b1, hbuf, N);

    const int MMB = 1024;   // 4096 waves, ~122 nodes/wave

    // layer 2
    agg64_kernel<<<(N + 3) / 4, 256, 0, stream>>>(hbuf, dinv, offs, cnt, csr, abuf, N);
    mm64_kernel<0><<<MMB, 256, 0, stream>>>(abuf, W2, b2, hbuf, nullptr, N);

    // layer 3 (matmul fused with mean-pool accumulation)
    agg64_kernel<<<(N + 3) / 4, 256, 0, stream>>>(hbuf, dinv, offs, cnt, csr, abuf, N);
    mm64_kernel<1><<<MMB, 256, 0, stream>>>(abuf, W3, b3, nullptr, pool, N);

    final_kernel<<<1, 64, 0, stream>>>(pool, Wfc, bfc, out, N);
}

// Round 4
// 592.201 us; speedup vs baseline: 4.1094x; 1.2422x over previous
//
#include <hip/hip_runtime.h>
#include <hip/hip_bf16.h>
#include <hip/hip_fp16.h>

// CircuitGNN: 3-layer GCN (N=500k, E=1M, H=64) + mean pool + tanh FC head.
// v4: fused layer kernel (CSR gather-aggregate + readlane matmul, no abuf),
//     h stored fp16 prescaled by dinv (hs = dinv.*h) -> both h buffers total
//     128 MB, L3-resident; no per-edge dinv gathers.
//     a_j = d_j*(hs_j + sum_{s in N(j)} hs_s);  h' = relu(a@W+b); store d_j*h'.
// History: v2 swizzled-LDS full-unroll spilled (VGPR 256, 1.9GB scratch) -- avoid.
//          v3 readlane register-stationary W: mm64 ~90us, agg64 была bottleneck.
// All compute fp32 (no fp32 MFMA on CDNA4); only storage is fp16.

#define ALIGN256(x) (((x) + 255) & ~(size_t)255)

__device__ __forceinline__ float rl(float v, int lane) {
    return __builtin_bit_cast(float, __builtin_amdgcn_readlane(__builtin_bit_cast(int, v), lane));
}

__global__ __launch_bounds__(256) void deg_kernel(const int* __restrict__ dst, int* __restrict__ cnt, int E) {
    int e = blockIdx.x * 256 + threadIdx.x;
    if (e < E) atomicAdd(&cnt[dst[e]], 1);
}

// dinv + prescaled xs (xs = dinv * x, padded to float4)
__global__ __launch_bounds__(256) void dinvx_kernel(const int* __restrict__ cnt, const float* __restrict__ x,
                                                    float* __restrict__ dinv, float4* __restrict__ xs, int N) {
    int i = blockIdx.x * 256 + threadIdx.x;
    if (i < N) {
        float d = rsqrtf((float)(cnt[i] + 1));   // +1 = self loop
        dinv[i] = d;
        xs[i] = make_float4(d * x[(size_t)i * 3 + 0], d * x[(size_t)i * 3 + 1],
                            d * x[(size_t)i * 3 + 2], 0.f);
    }
}

// ---- 2-level exclusive scan over cnt[N] ----
__global__ __launch_bounds__(256) void scan1_kernel(const int* __restrict__ cnt, int* __restrict__ bsum, int N) {
    __shared__ int s[256];
    int t = threadIdx.x, b = blockIdx.x;
    int i0 = b * 1024 + t * 4;
    int v = 0;
    if (i0 + 3 < N) { int4 q = *(const int4*)&cnt[i0]; v = q.x + q.y + q.z + q.w; }
    else { for (int k = 0; k < 4; ++k) if (i0 + k < N) v += cnt[i0 + k]; }
    s[t] = v; __syncthreads();
    for (int o = 128; o > 0; o >>= 1) { if (t < o) s[t] += s[t + o]; __syncthreads(); }
    if (t == 0) bsum[b] = s[0];
}

__global__ __launch_bounds__(512) void scan2_kernel(const int* __restrict__ bsum, int* __restrict__ bbase, int nb) {
    __shared__ int s[512];
    int t = threadIdx.x;
    int v = (t < nb) ? bsum[t] : 0;
    s[t] = v; __syncthreads();
    for (int off = 1; off < 512; off <<= 1) {
        int u = 0; if (t >= off) u = s[t - off];
        __syncthreads(); s[t] += u; __syncthreads();
    }
    if (t < nb) bbase[t] = s[t] - v;   // exclusive
}

// writes od[j] = (offset, deg) and cur[j] = offset
__global__ __launch_bounds__(256) void scan3_kernel(const int* __restrict__ cnt, const int* __restrict__ bbase,
                                                    int2* __restrict__ od, int* __restrict__ cur, int N) {
    __shared__ int s[256];
    int t = threadIdx.x, b = blockIdx.x;
    int i0 = b * 1024 + t * 4;
    int v0 = 0, v1 = 0, v2 = 0, v3 = 0;
    if (i0 + 3 < N) { int4 q = *(const int4*)&cnt[i0]; v0 = q.x; v1 = q.y; v2 = q.z; v3 = q.w; }
    else {
        if (i0 < N) v0 = cnt[i0];
        if (i0 + 1 < N) v1 = cnt[i0 + 1];
        if (i0 + 2 < N) v2 = cnt[i0 + 2];
        if (i0 + 3 < N) v3 = cnt[i0 + 3];
    }
    int ts = v0 + v1 + v2 + v3;
    s[t] = ts; __syncthreads();
    for (int off = 1; off < 256; off <<= 1) {
        int u = 0; if (t >= off) u = s[t - off];
        __syncthreads(); s[t] += u; __syncthreads();
    }
    int ex = s[t] - ts + bbase[b];
    int o0 = ex, o1 = ex + v0, o2 = o1 + v1, o3 = o2 + v2;
    if (i0     < N) { od[i0]     = make_int2(o0, v0); cur[i0]     = o0; }
    if (i0 + 1 < N) { od[i0 + 1] = make_int2(o1, v1); cur[i0 + 1] = o1; }
    if (i0 + 2 < N) { od[i0 + 2] = make_int2(o2, v2); cur[i0 + 2] = o2; }
    if (i0 + 3 < N) { od[i0 + 3] = make_int2(o3, v3); cur[i0 + 3] = o3; }
}

__global__ __launch_bounds__(256) void fill_kernel(const int* __restrict__ ei, int* __restrict__ cur,
                                                   int* __restrict__ csr, int E) {
    int e = blockIdx.x * 256 + threadIdx.x;
    if (e < E) {
        int s = ei[e], d = ei[E + e];
        int p = atomicAdd(&cur[d], 1);
        csr[p] = s;
    }
}

// ---- layer 1 aggregate (thread per node, xs prescaled): a1 = dj*(xs_j + sum xs_s) ----
__global__ __launch_bounds__(256) void agg1_kernel(const float4* __restrict__ xs, const float* __restrict__ dinv,
                                                   const int2* __restrict__ od, const int* __restrict__ csr,
                                                   float4* __restrict__ a1, int N) {
    int j = blockIdx.x * 256 + threadIdx.x;
    if (j >= N) return;
    float4 s = xs[j];
    int2 o = od[j];
    for (int i = 0; i < o.y; ++i) {
        float4 q = xs[csr[o.x + i]];
        s.x += q.x; s.y += q.y; s.z += q.z;
    }
    float dj = dinv[j];
    a1[j] = make_float4(dj * s.x, dj * s.y, dj * s.z, 0.f);
}

// ---- layer 1 matmul 3->64, wave grid-stride, writes prescaled fp16 ----
__global__ __launch_bounds__(256) void mm1_kernel(const float4* __restrict__ a1, const float* __restrict__ dinv,
                                                  const float* __restrict__ W1, const float* __restrict__ b1,
                                                  __half* __restrict__ hout, int N) {
    const int l = threadIdx.x & 63;
    const int wave = blockIdx.x * 4 + (threadIdx.x >> 6);
    const int stride = gridDim.x * 4;
    const float w0 = W1[l], w1 = W1[64 + l], w2 = W1[128 + l], bl = b1[l];
    for (int j = wave; j < N; j += stride) {
        float4 a = a1[j];
        float dj = dinv[j];
        float v = fmaf(a.x, w0, fmaf(a.y, w1, fmaf(a.z, w2, bl)));
        hout[(size_t)j * 64 + l] = __float2half(dj * fmaxf(v, 0.f));
    }
}

// ---- fused GCN layer: gather-aggregate (fp16 rows) + readlane matmul.
//      POOL=1 accumulates mean-pool numerator instead of storing. ----
template <int POOL>
__global__ __launch_bounds__(256) void layer_kernel(const __half* __restrict__ hin, const float* __restrict__ dinv,
                                                    const int2* __restrict__ od, const int* __restrict__ csr,
                                                    const float* __restrict__ W, const float* __restrict__ bias,
                                                    __half* __restrict__ hout, float* __restrict__ pool, int N) {
    const int l = threadIdx.x & 63;
    const int wave = blockIdx.x * 4 + (threadIdx.x >> 6);
    const int stride = gridDim.x * 4;

    // W register-stationary: lane l holds column l (64 VGPRs)
    float w[64];
    #pragma unroll
    for (int k = 0; k < 64; ++k) w[k] = W[k * 64 + l];
    const float bl = bias[l];

    float ps = 0.f;
    for (int j = wave; j < N; j += stride) {
        int2 o = od[j];
        float dj = dinv[j];
        float acc = __half2float(hin[(size_t)j * 64 + l]);   // self (prescaled)
        const int* cp = csr + o.x;
        int i = 0;
        for (; i + 1 < o.y; i += 2) {
            int s0 = cp[i], s1 = cp[i + 1];
            float g0 = __half2float(hin[(size_t)s0 * 64 + l]);
            float g1 = __half2float(hin[(size_t)s1 * 64 + l]);
            acc += g0 + g1;
        }
        if (i < o.y) acc += __half2float(hin[(size_t)cp[i] * 64 + l]);
        float a = dj * acc;

        float acc0 = 0.f, acc1 = 0.f, acc2 = 0.f, acc3 = 0.f;
        #pragma unroll
        for (int k = 0; k < 64; k += 4) {
            acc0 = fmaf(rl(a, k + 0), w[k + 0], acc0);
            acc1 = fmaf(rl(a, k + 1), w[k + 1], acc1);
            acc2 = fmaf(rl(a, k + 2), w[k + 2], acc2);
            acc3 = fmaf(rl(a, k + 3), w[k + 3], acc3);
        }
        float r = fmaxf((acc0 + acc1) + (acc2 + acc3) + bl, 0.f);
        if (POOL) ps += r;
        else hout[(size_t)j * 64 + l] = __float2half(dj * r);
    }

    if (POOL) {
        __shared__ float red[256];
        red[threadIdx.x] = ps;
        __syncthreads();
        if (threadIdx.x < 64) {
            float s = red[threadIdx.x] + red[64 + threadIdx.x]
                    + red[128 + threadIdx.x] + red[192 + threadIdx.x];
            atomicAdd(&pool[threadIdx.x], s);
        }
    }
}

__global__ __launch_bounds__(64) void final_kernel(const float* __restrict__ pool, const float* __restrict__ Wfc,
                                                   const float* __restrict__ bfc, float* __restrict__ out, int N) {
    int t = threadIdx.x;
    if (t < 24) {
        float inv = 1.0f / (float)N;
        float s = bfc[t];
        for (int c = 0; c < 64; ++c) s += pool[c] * inv * Wfc[c * 24 + t];
        out[t] = tanhf(s);
    }
}

extern "C" void kernel_launch(void* const* d_in, const int* in_sizes, int n_in,
                              void* d_out, int out_size, void* d_ws, size_t ws_size,
                              hipStream_t stream) {
    const float* x   = (const float*)d_in[0];
    const int*   ei  = (const int*)d_in[1];     // (2,E): row0 = src, row1 = dst
    // d_in[2] = batch (all zeros) -- unused
    const float* W1  = (const float*)d_in[3];
    const float* b1  = (const float*)d_in[4];
    const float* W2  = (const float*)d_in[5];
    const float* b2  = (const float*)d_in[6];
    const float* W3  = (const float*)d_in[7];
    const float* b3  = (const float*)d_in[8];
    const float* Wfc = (const float*)d_in[9];
    const float* bfc = (const float*)d_in[10];
    float* out = (float*)d_out;

    const int N = in_sizes[2];          // batch length = num nodes
    const int E = in_sizes[1] / 2;

    size_t off = 0;
    auto take = [&](size_t bytes) -> char* {
        char* p = (char*)d_ws + off;
        off = ALIGN256(off + bytes);
        return p;
    };
    int*    cnt   = (int*)   take((size_t)N * 4);
    float*  dinv  = (float*) take((size_t)N * 4);
    int2*   od    = (int2*)  take((size_t)N * 8);
    int*    cur   = (int*)   take((size_t)N * 4);
    int*    bsum  = (int*)   take(512 * 4);
    int*    bbase = (int*)   take(512 * 4);
    float*  pool  = (float*) take(64 * 4);
    int*    csr   = (int*)   take((size_t)E * 4);
    float4* xs    = (float4*)take((size_t)N * 16);
    float4* a1    = (float4*)take((size_t)N * 16);
    __half* h16a  = (__half*)take((size_t)N * 64 * 2);
    __half* h16b  = (__half*)take((size_t)N * 64 * 2);
    (void)ws_size; (void)n_in; (void)out_size;

    const int NB = (N + 1023) / 1024;   // <= 512 for N <= 512k

    hipMemsetAsync(cnt, 0, (size_t)N * 4, stream);
    hipMemsetAsync(pool, 0, 64 * 4, stream);

    deg_kernel  <<<(E + 255) / 256, 256, 0, stream>>>(ei + E, cnt, E);
    dinvx_kernel<<<(N + 255) / 256, 256, 0, stream>>>(cnt, x, dinv, xs, N);
    scan1_kernel<<<NB, 256, 0, stream>>>(cnt, bsum, N);
    scan2_kernel<<<1, 512, 0, stream>>>(bsum, bbase, NB);
    scan3_kernel<<<NB, 256, 0, stream>>>(cnt, bbase, od, cur, N);
    fill_kernel <<<(E + 255) / 256, 256, 0, stream>>>(ei, cur, csr, E);

    // layer 1: a1 = S@xs, hs1 = dinv.*relu(a1@W1 + b1)  (fp16)
    agg1_kernel<<<(N + 255) / 256, 256, 0, stream>>>(xs, dinv, od, csr, a1, N);
    mm1_kernel <<<1280, 256, 0, stream>>>(a1, dinv, W1, b1, h16a, N);

    const int LB = 1280;    // 5120 waves, ~98 nodes/wave

    // layer 2 (fused aggregate + matmul), hs2 = dinv.*relu((S@h1)@W2+b2)
    layer_kernel<0><<<LB, 256, 0, stream>>>(h16a, dinv, od, csr, W2, b2, h16b, nullptr, N);

    // layer 3 fused with mean-pool accumulation
    layer_kernel<1><<<LB, 256, 0, stream>>>(h16b, dinv, od, csr, W3, b3, nullptr, pool, N);

    final_kernel<<<1, 64, 0, stream>>>(pool, Wfc, bfc, out, N);
}

// Round 5
// 537.372 us; speedup vs baseline: 4.5287x; 1.1020x over previous
//
#include <hip/hip_runtime.h>
#include <hip/hip_bf16.h>
#include <hip/hip_fp16.h>

// CircuitGNN: 3-layer GCN (N=500k, E=1M, H=64) + mean pool + tanh FC head.
// v5: fused layer kernel, wave = 16 nodes/group:
//     Phase A: lane-per-feature CSR gather-sum per node -> a=dj*acc -> fp16 ->
//              per-wave LDS tile (16 x 136 padded, no cross-wave sync).
//     Phase B: 2x ds_read_b128 A-frags + 8x mfma_f32_16x16x32_f16 vs
//              register-stationary W fragments (loaded once, 32 VGPRs).
//     Epilogue: C layout col=lane&15,row=quad*4+reg; bias+relu+dj scale;
//              POOL=1 accumulates mean-pool in regs, block-reduce after loop.
// History: v2 swizzled-LDS full-unroll spilled (VGPR 256, 1.9GB scratch) -- avoid.
//          v3/v4 readlane matmul: correct but 128 VALU insts/node -> issue-bound
//          (VALUBusy 58%). v4 fp16 prescaled h (both buffers L3-resident).
// Storage fp16; compute fp32 (MFMA f16-in/f32-acc).

#define ALIGN256(x) (((x) + 255) & ~(size_t)255)

typedef _Float16 half8 __attribute__((ext_vector_type(8)));
typedef float f32x4 __attribute__((ext_vector_type(4)));

__device__ __forceinline__ float rl(float v, int lane) {
    return __builtin_bit_cast(float, __builtin_amdgcn_readlane(__builtin_bit_cast(int, v), lane));
}

__global__ __launch_bounds__(256) void deg_kernel(const int* __restrict__ dst, int* __restrict__ cnt, int E) {
    int e = blockIdx.x * 256 + threadIdx.x;
    if (e < E) atomicAdd(&cnt[dst[e]], 1);
}

// dinv + prescaled xs (xs = dinv * x, padded to float4)
__global__ __launch_bounds__(256) void dinvx_kernel(const int* __restrict__ cnt, const float* __restrict__ x,
                                                    float* __restrict__ dinv, float4* __restrict__ xs, int N) {
    int i = blockIdx.x * 256 + threadIdx.x;
    if (i < N) {
        float d = rsqrtf((float)(cnt[i] + 1));   // +1 = self loop
        dinv[i] = d;
        xs[i] = make_float4(d * x[(size_t)i * 3 + 0], d * x[(size_t)i * 3 + 1],
                            d * x[(size_t)i * 3 + 2], 0.f);
    }
}

// ---- 2-level exclusive scan over cnt[N] ----
__global__ __launch_bounds__(256) void scan1_kernel(const int* __restrict__ cnt, int* __restrict__ bsum, int N) {
    __shared__ int s[256];
    int t = threadIdx.x, b = blockIdx.x;
    int i0 = b * 1024 + t * 4;
    int v = 0;
    if (i0 + 3 < N) { int4 q = *(const int4*)&cnt[i0]; v = q.x + q.y + q.z + q.w; }
    else { for (int k = 0; k < 4; ++k) if (i0 + k < N) v += cnt[i0 + k]; }
    s[t] = v; __syncthreads();
    for (int o = 128; o > 0; o >>= 1) { if (t < o) s[t] += s[t + o]; __syncthreads(); }
    if (t == 0) bsum[b] = s[0];
}

__global__ __launch_bounds__(512) void scan2_kernel(const int* __restrict__ bsum, int* __restrict__ bbase, int nb) {
    __shared__ int s[512];
    int t = threadIdx.x;
    int v = (t < nb) ? bsum[t] : 0;
    s[t] = v; __syncthreads();
    for (int off = 1; off < 512; off <<= 1) {
        int u = 0; if (t >= off) u = s[t - off];
        __syncthreads(); s[t] += u; __syncthreads();
    }
    if (t < nb) bbase[t] = s[t] - v;   // exclusive
}

// writes od[j] = (offset, deg) and cur[j] = offset
__global__ __launch_bounds__(256) void scan3_kernel(const int* __restrict__ cnt, const int* __restrict__ bbase,
                                                    int2* __restrict__ od, int* __restrict__ cur, int N) {
    __shared__ int s[256];
    int t = threadIdx.x, b = blockIdx.x;
    int i0 = b * 1024 + t * 4;
    int v0 = 0, v1 = 0, v2 = 0, v3 = 0;
    if (i0 + 3 < N) { int4 q = *(const int4*)&cnt[i0]; v0 = q.x; v1 = q.y; v2 = q.z; v3 = q.w; }
    else {
        if (i0 < N) v0 = cnt[i0];
        if (i0 + 1 < N) v1 = cnt[i0 + 1];
        if (i0 + 2 < N) v2 = cnt[i0 + 2];
        if (i0 + 3 < N) v3 = cnt[i0 + 3];
    }
    int ts = v0 + v1 + v2 + v3;
    s[t] = ts; __syncthreads();
    for (int off = 1; off < 256; off <<= 1) {
        int u = 0; if (t >= off) u = s[t - off];
        __syncthreads(); s[t] += u; __syncthreads();
    }
    int ex = s[t] - ts + bbase[b];
    int o0 = ex, o1 = ex + v0, o2 = o1 + v1, o3 = o2 + v2;
    if (i0     < N) { od[i0]     = make_int2(o0, v0); cur[i0]     = o0; }
    if (i0 + 1 < N) { od[i0 + 1] = make_int2(o1, v1); cur[i0 + 1] = o1; }
    if (i0 + 2 < N) { od[i0 + 2] = make_int2(o2, v2); cur[i0 + 2] = o2; }
    if (i0 + 3 < N) { od[i0 + 3] = make_int2(o3, v3); cur[i0 + 3] = o3; }
}

__global__ __launch_bounds__(256) void fill_kernel(const int* __restrict__ ei, int* __restrict__ cur,
                                                   int* __restrict__ csr, int E) {
    int e = blockIdx.x * 256 + threadIdx.x;
    if (e < E) {
        int s = ei[e], d = ei[E + e];
        int p = atomicAdd(&cur[d], 1);
        csr[p] = s;
    }
}

// ---- layer 1 aggregate (thread per node, xs prescaled): a1 = dj*(xs_j + sum xs_s) ----
__global__ __launch_bounds__(256) void agg1_kernel(const float4* __restrict__ xs, const float* __restrict__ dinv,
                                                   const int2* __restrict__ od, const int* __restrict__ csr,
                                                   float4* __restrict__ a1, int N) {
    int j = blockIdx.x * 256 + threadIdx.x;
    if (j >= N) return;
    float4 s = xs[j];
    int2 o = od[j];
    for (int i = 0; i < o.y; ++i) {
        float4 q = xs[csr[o.x + i]];
        s.x += q.x; s.y += q.y; s.z += q.z;
    }
    float dj = dinv[j];
    a1[j] = make_float4(dj * s.x, dj * s.y, dj * s.z, 0.f);
}

// ---- layer 1 matmul 3->64, wave grid-stride, writes prescaled fp16 ----
__global__ __launch_bounds__(256) void mm1_kernel(const float4* __restrict__ a1, const float* __restrict__ dinv,
                                                  const float* __restrict__ W1, const float* __restrict__ b1,
                                                  __half* __restrict__ hout, int N) {
    const int l = threadIdx.x & 63;
    const int wave = blockIdx.x * 4 + (threadIdx.x >> 6);
    const int stride = gridDim.x * 4;
    const float w0 = W1[l], w1 = W1[64 + l], w2 = W1[128 + l], bl = b1[l];
    for (int j = wave; j < N; j += stride) {
        float4 a = a1[j];
        float dj = dinv[j];
        float v = fmaf(a.x, w0, fmaf(a.y, w1, fmaf(a.z, w2, bl)));
        hout[(size_t)j * 64 + l] = __float2half(dj * fmaxf(v, 0.f));
    }
}

// ---- fused GCN layer v5: wave = 16 nodes; gather-aggregate into per-wave LDS
//      tile (fp16, A-frag layout), then 8x mfma_f32_16x16x32_f16.
//      POOL=1 accumulates mean-pool numerator in registers. ----
template <int POOL>
__global__ __launch_bounds__(256) void layer_kernel(const __half* __restrict__ hin, const float* __restrict__ dinv,
                                                    const int2* __restrict__ od, const int* __restrict__ csr,
                                                    const float* __restrict__ W, const float* __restrict__ bias,
                                                    __half* __restrict__ hout, float* __restrict__ pool, int N) {
    const int t = threadIdx.x;
    const int l = t & 63;
    const int w = t >> 6;
    const int l15 = l & 15, q = l >> 4;

    __shared__ _Float16 aS[4][16 * 136 + 8];   // per-wave slice, row stride 136 (272 B)
    __shared__ float red[256];
    _Float16* as = aS[w];

    // B fragments of W (fp32 global -> f16 regs): b[ct][kt], lane holds
    // B[k = kt*32 + q*8 + j][col = ct*16 + l15], j=0..7. One-time, L2-hot.
    half8 bfr[4][2];
    #pragma unroll
    for (int ct = 0; ct < 4; ++ct)
        #pragma unroll
        for (int kt = 0; kt < 2; ++kt) {
            half8 b;
            #pragma unroll
            for (int j = 0; j < 8; ++j)
                b[j] = (_Float16)W[(kt * 32 + q * 8 + j) * 64 + ct * 16 + l15];
            bfr[ct][kt] = b;
        }
    float bb[4];
    #pragma unroll
    for (int ct = 0; ct < 4; ++ct) bb[ct] = bias[ct * 16 + l15];

    float ps0 = 0.f, ps1 = 0.f, ps2 = 0.f, ps3 = 0.f;

    const int ngroups = (N + 15) >> 4;
    const int gstride = gridDim.x * 4;
    for (int g = blockIdx.x * 4 + w; g < ngroups; g += gstride) {
        const int j0 = g << 4;
        // prefetch od/dinv for the group's 16 nodes (lanes 0..15, coalesced)
        float djv = 0.f; int oxv = 0, oyv = 0;
        if (l < 16 && j0 + l < N) {
            int2 o = od[j0 + l];
            oxv = o.x; oyv = o.y;
            djv = dinv[j0 + l];
        }
        // Phase A: aggregate node j0+m, lane = feature l
        for (int m = 0; m < 16; ++m) {
            int j = j0 + m;
            if (j >= N) break;                                   // uniform
            int off = __builtin_amdgcn_readlane(oxv, m);
            int deg = __builtin_amdgcn_readlane(oyv, m);
            float dj = rl(djv, m);
            float acc = __half2float(hin[(size_t)j * 64 + l]);   // self (prescaled)
            const int* cp = csr + off;
            int i = 0;
            for (; i + 1 < deg; i += 2) {
                int s0 = cp[i], s1 = cp[i + 1];
                acc += __half2float(hin[(size_t)s0 * 64 + l])
                     + __half2float(hin[(size_t)s1 * 64 + l]);
            }
            if (i < deg) acc += __half2float(hin[(size_t)cp[i] * 64 + l]);
            as[m * 136 + l] = (_Float16)(dj * acc);
        }
        __asm__ volatile("s_waitcnt lgkmcnt(0)" ::: "memory");

        // Phase B: A-frags (A[m=l15][k=q*8+j] per ktile) + 8 MFMA
        half8 af0 = *(const half8*)&as[l15 * 136 + q * 8];
        half8 af1 = *(const half8*)&as[l15 * 136 + 32 + q * 8];
        f32x4 c0 = {0.f, 0.f, 0.f, 0.f}, c1 = c0, c2 = c0, c3 = c0;
        c0 = __builtin_amdgcn_mfma_f32_16x16x32_f16(af0, bfr[0][0], c0, 0, 0, 0);
        c1 = __builtin_amdgcn_mfma_f32_16x16x32_f16(af0, bfr[1][0], c1, 0, 0, 0);
        c2 = __builtin_amdgcn_mfma_f32_16x16x32_f16(af0, bfr[2][0], c2, 0, 0, 0);
        c3 = __builtin_amdgcn_mfma_f32_16x16x32_f16(af0, bfr[3][0], c3, 0, 0, 0);
        c0 = __builtin_amdgcn_mfma_f32_16x16x32_f16(af1, bfr[0][1], c0, 0, 0, 0);
        c1 = __builtin_amdgcn_mfma_f32_16x16x32_f16(af1, bfr[1][1], c1, 0, 0, 0);
        c2 = __builtin_amdgcn_mfma_f32_16x16x32_f16(af1, bfr[2][1], c2, 0, 0, 0);
        c3 = __builtin_amdgcn_mfma_f32_16x16x32_f16(af1, bfr[3][1], c3, 0, 0, 0);

        // Epilogue: C[row = q*4+r][col = ct*16+l15]
        if (POOL) {
            #pragma unroll
            for (int r = 0; r < 4; ++r) {
                int gj = j0 + q * 4 + r;
                if (gj < N) {
                    ps0 += fmaxf(c0[r] + bb[0], 0.f);
                    ps1 += fmaxf(c1[r] + bb[1], 0.f);
                    ps2 += fmaxf(c2[r] + bb[2], 0.f);
                    ps3 += fmaxf(c3[r] + bb[3], 0.f);
                }
            }
        } else {
            #pragma unroll
            for (int r = 0; r < 4; ++r) {
                int row = q * 4 + r;
                int gj = j0 + row;
                float djr = __shfl(djv, row, 64);
                if (gj < N) {
                    size_t base = (size_t)gj * 64 + l15;
                    hout[base]      = __float2half(djr * fmaxf(c0[r] + bb[0], 0.f));
                    hout[base + 16] = __float2half(djr * fmaxf(c1[r] + bb[1], 0.f));
                    hout[base + 32] = __float2half(djr * fmaxf(c2[r] + bb[2], 0.f));
                    hout[base + 48] = __float2half(djr * fmaxf(c3[r] + bb[3], 0.f));
                }
            }
        }
    }

    if (POOL) {
        // quad-reduce within wave (cols identical across quads after xor 16,32)
        ps0 += __shfl_xor(ps0, 16, 64); ps0 += __shfl_xor(ps0, 32, 64);
        ps1 += __shfl_xor(ps1, 16, 64); ps1 += __shfl_xor(ps1, 32, 64);
        ps2 += __shfl_xor(ps2, 16, 64); ps2 += __shfl_xor(ps2, 32, 64);
        ps3 += __shfl_xor(ps3, 16, 64); ps3 += __shfl_xor(ps3, 32, 64);
        if (q == 0) {
            red[w * 64 + l15]      = ps0;
            red[w * 64 + 16 + l15] = ps1;
            red[w * 64 + 32 + l15] = ps2;
            red[w * 64 + 48 + l15] = ps3;
        }
        __syncthreads();
        if (t < 64) {
            float s = red[t] + red[64 + t] + red[128 + t] + red[192 + t];
            atomicAdd(&pool[t], s);
        }
    }
}

__global__ __launch_bounds__(64) void final_kernel(const float* __restrict__ pool, const float* __restrict__ Wfc,
                                                   const float* __restrict__ bfc, float* __restrict__ out, int N) {
    int t = threadIdx.x;
    if (t < 24) {
        float inv = 1.0f / (float)N;
        float s = bfc[t];
        for (int c = 0; c < 64; ++c) s += pool[c] * inv * Wfc[c * 24 + t];
        out[t] = tanhf(s);
    }
}

extern "C" void kernel_launch(void* const* d_in, const int* in_sizes, int n_in,
                              void* d_out, int out_size, void* d_ws, size_t ws_size,
                              hipStream_t stream) {
    const float* x   = (const float*)d_in[0];
    const int*   ei  = (const int*)d_in[1];     // (2,E): row0 = src, row1 = dst
    // d_in[2] = batch (all zeros) -- unused
    const float* W1  = (const float*)d_in[3];
    const float* b1  = (const float*)d_in[4];
    const float* W2  = (const float*)d_in[5];
    const float* b2  = (const float*)d_in[6];
    const float* W3  = (const float*)d_in[7];
    const float* b3  = (const float*)d_in[8];
    const float* Wfc = (const float*)d_in[9];
    const float* bfc = (const float*)d_in[10];
    float* out = (float*)d_out;

    const int N = in_sizes[2];          // batch length = num nodes
    const int E = in_sizes[1] / 2;

    size_t off = 0;
    auto take = [&](size_t bytes) -> char* {
        char* p = (char*)d_ws + off;
        off = ALIGN256(off + bytes);
        return p;
    };
    int*    cnt   = (int*)   take((size_t)N * 4);
    float*  dinv  = (float*) take((size_t)N * 4);
    int2*   od    = (int2*)  take((size_t)N * 8);
    int*    cur   = (int*)   take((size_t)N * 4);
    int*    bsum  = (int*)   take(512 * 4);
    int*    bbase = (int*)   take(512 * 4);
    float*  pool  = (float*) take(64 * 4);
    int*    csr   = (int*)   take((size_t)E * 4);
    float4* xs    = (float4*)take((size_t)N * 16);
    float4* a1    = (float4*)take((size_t)N * 16);
    __half* h16a  = (__half*)take((size_t)N * 64 * 2);
    __half* h16b  = (__half*)take((size_t)N * 64 * 2);
    (void)ws_size; (void)n_in; (void)out_size;

    const int NB = (N + 1023) / 1024;   // <= 512 for N <= 512k

    hipMemsetAsync(cnt, 0, (size_t)N * 4, stream);
    hipMemsetAsync(pool, 0, 64 * 4, stream);

    deg_kernel  <<<(E + 255) / 256, 256, 0, stream>>>(ei + E, cnt, E);
    dinvx_kernel<<<(N + 255) / 256, 256, 0, stream>>>(cnt, x, dinv, xs, N);
    scan1_kernel<<<NB, 256, 0, stream>>>(cnt, bsum, N);
    scan2_kernel<<<1, 512, 0, stream>>>(bsum, bbase, NB);
    scan3_kernel<<<NB, 256, 0, stream>>>(cnt, bbase, od, cur, N);
    fill_kernel <<<(E + 255) / 256, 256, 0, stream>>>(ei, cur, csr, E);

    // layer 1: a1 = S@xs, hs1 = dinv.*relu(a1@W1 + b1)  (fp16)
    agg1_kernel<<<(N + 255) / 256, 256, 0, stream>>>(xs, dinv, od, csr, a1, N);
    mm1_kernel <<<1280, 256, 0, stream>>>(a1, dinv, W1, b1, h16a, N);

    const int LB = 768;    // 3072 waves, ~10 groups (160 nodes) per wave

    // layer 2 (fused aggregate + MFMA matmul), hs2 = dinv.*relu((S@h1)@W2+b2)
    layer_kernel<0><<<LB, 256, 0, stream>>>(h16a, dinv, od, csr, W2, b2, h16b, nullptr, N);

    // layer 3 fused with mean-pool accumulation
    layer_kernel<1><<<LB, 256, 0, stream>>>(h16b, dinv, od, csr, W3, b3, nullptr, pool, N);

    final_kernel<<<1, 64, 0, stream>>>(pool, Wfc, bfc, out, N);
}